// Round 4
// baseline (907.756 us; speedup 1.0000x reference)
//
#include <hip/hip_runtime.h>
#include <stdint.h>

// Problem: B=16, S=512, H=2048, NH=16, NKV=4, HD=128
// out = Wo-proj( softmax(rope(q) @ rope(k)^T * hd^-.5) @ v )  with GQA rep=4
//
// ws layout (f16 intermediates):
//   x_h   [8192,2048]        @ 0
//   w_h   [3072,2048]        @ 33554432  (Wq 0..2047, Wk 2048..2559, Wv 2560..3071)
//   wo_h  [2048,2048]        @ 46137344
//   q     [16,16,512,128]    @ 54525952   (RoPE fused in gemm_qkv epilogue)
//   k     [16,4,512,128]     @ 88080384   (RoPE fused)
//   vt    [16,4,128,512]     @ 96468992   (V transposed)
//   attn  [8192,2048]        @ 104857600
//
// R3 lesson: occupancy > bank conflicts on the m97 structure. 4x4+swizzle
// ballooned VGPR 76->104 (4 waves/SIMD) and regressed despite 0 conflicts.
// R4: keep swizzle, cap with __launch_bounds__(256,5) (VGPR<=102, 5 waves).

typedef _Float16 f16;
typedef _Float16 f16x4 __attribute__((ext_vector_type(4)));
typedef _Float16 f16x8 __attribute__((ext_vector_type(8)));
typedef float f32x4 __attribute__((ext_vector_type(4)));

#define B_   16
#define S_   512
#define H_   2048
#define NH_  16
#define NKV_ 4
#define HD_  128
#define ATT_SCALE 0.08838834764831843f
#define LOG2_10000_DIV64 0.20762050593045952f

#define AS1 __attribute__((address_space(1)))
#define AS3 __attribute__((address_space(3)))

// async global->LDS, 16B/lane. LDS dest must be wave-uniform; HW adds lane*16.
__device__ __forceinline__ void async16(const void* g, const void* l) {
  __builtin_amdgcn_global_load_lds((const AS1 unsigned int*)(uintptr_t)g,
                                   (AS3 unsigned int*)(uintptr_t)l, 16, 0, 0);
}

// ---------------- fused fp32 -> f16 cast for all 5 inputs ----------------
__global__ __launch_bounds__(256) void cast_all(const float* __restrict__ x,
                                                const float* __restrict__ wq,
                                                const float* __restrict__ wk,
                                                const float* __restrict__ wv,
                                                const float* __restrict__ wo,
                                                f16* __restrict__ x_h,
                                                f16* __restrict__ w_h,
                                                f16* __restrict__ wo_h) {
  const int i = blockIdx.x * 256 + threadIdx.x;
  const float4* src;
  f16x4* dst;
  if (i < 4194304) {                 // x: 8192*2048
    src = (const float4*)x + i;            dst = (f16x4*)x_h + i;
  } else if (i < 5242880) {          // Wq: 2048*2048
    int j = i - 4194304;
    src = (const float4*)wq + j;           dst = (f16x4*)w_h + j;
  } else if (i < 5505024) {          // Wk: 512*2048
    int j = i - 5242880;
    src = (const float4*)wk + j;           dst = (f16x4*)w_h + 1048576 + j;
  } else if (i < 5767168) {          // Wv: 512*2048
    int j = i - 5505024;
    src = (const float4*)wv + j;           dst = (f16x4*)w_h + 1310720 + j;
  } else {                           // Wo: 2048*2048
    int j = i - 5767168;
    src = (const float4*)wo + j;           dst = (f16x4*)wo_h + j;
  }
  float4 v = *src;
  f16x4 o = {(f16)v.x, (f16)v.y, (f16)v.z, (f16)v.w};
  *dst = o;
}

// LDS chunk swizzle for 64B-row tiles: chunk (r,c) at slot c ^ ((r>>1)&3).
__device__ __forceinline__ int swz(int r, int c) { return c ^ ((r >> 1) & 3); }

// ---------------- GEMM1: qkv = x @ Wqkv^T, fused RoPE + scatter epilogue ----
// Wave tile 64x64, cols split {wn*32..+31} u {64+wn*32..+31} so the RoPE pair
// (d, d+64) is acc[mi][ni]/acc[mi][ni+2] in the same lane.
__global__ __launch_bounds__(256, 5) void gemm_qkv(const f16* __restrict__ A,
                                                   const f16* __restrict__ W,
                                                   f16* __restrict__ qo,
                                                   f16* __restrict__ ko,
                                                   f16* __restrict__ vto) {
  __shared__ __align__(16) f16 As[128 * 32];
  __shared__ __align__(16) f16 Bs[128 * 32];
  const int K = 2048;
  const int m0 = blockIdx.x * 128;
  const int n0 = blockIdx.y * 128;
  const int tid = threadIdx.x;
  const int wave = tid >> 6, lane = tid & 63;
  const int quad = lane >> 4, l15 = lane & 15;
  const int wm = wave >> 1, wn = wave & 1;
  const int G0 = wave * 128 + lane;
  const int r0 = G0 >> 2, c0g = swz(r0, G0 & 3);
  const int r1 = (G0 + 64) >> 2, c1g = swz(r1, (G0 + 64) & 3);

  f32x4 acc[4][4] = {};

  for (int k0 = 0; k0 < K; k0 += 32) {
    async16(A + (size_t)(m0 + r0) * K + k0 + c0g * 8, (const char*)As + (size_t)G0 * 16);
    async16(A + (size_t)(m0 + r1) * K + k0 + c1g * 8, (const char*)As + (size_t)(G0 + 64) * 16);
    async16(W + (size_t)(n0 + r0) * K + k0 + c0g * 8, (const char*)Bs + (size_t)G0 * 16);
    async16(W + (size_t)(n0 + r1) * K + k0 + c1g * 8, (const char*)Bs + (size_t)(G0 + 64) * 16);
    __syncthreads();  // drains vmcnt -> staging visible
    f16x8 b[4];
#pragma unroll
    for (int ni = 0; ni < 4; ++ni) {
      const int col = (ni >> 1) * 64 + wn * 32 + (ni & 1) * 16 + l15;
      b[ni] = *reinterpret_cast<const f16x8*>(Bs + col * 32 + swz(col, quad) * 8);
    }
#pragma unroll
    for (int mi = 0; mi < 4; ++mi) {   // short a live-range: load, use, retire
      const int row = wm * 64 + mi * 16 + l15;
      const f16x8 a = *reinterpret_cast<const f16x8*>(As + row * 32 + swz(row, quad) * 8);
#pragma unroll
      for (int ni = 0; ni < 4; ++ni)
        acc[mi][ni] = __builtin_amdgcn_mfma_f32_16x16x32_f16(a, b[ni], acc[mi][ni], 0, 0, 0);
    }
    __syncthreads();  // before next-tile overwrite
  }

  const int b_ = m0 >> 9;  // batch (uniform per block)
  if (n0 >= 2560) {
    // ---- V: no rope, store transposed [b, kh, d, s] ----
    const int h = (n0 - 2560) >> 7;
    f16* vb = vto + ((size_t)b_ * NKV_ + h) * HD_ * S_;
#pragma unroll
    for (int mi = 0; mi < 4; ++mi)
#pragma unroll
      for (int r = 0; r < 4; ++r) {
        const int s = (m0 + wm * 64 + mi * 16 + quad * 4 + r) & 511;
#pragma unroll
        for (int ni = 0; ni < 4; ++ni) {
          const int d = (ni >> 1) * 64 + wn * 32 + (ni & 1) * 16 + l15;
          vb[(size_t)d * S_ + s] = (f16)acc[mi][ni][r];
        }
      }
  } else {
    // ---- Q or K: fused RoPE, store [b, h, s, d] ----
    f16* ob = (n0 < 2048) ? (qo + ((size_t)b_ * NH_ + (n0 >> 7)) * S_ * HD_)
                          : (ko + ((size_t)b_ * NKV_ + ((n0 - 2048) >> 7)) * S_ * HD_);
    float invf[2];
#pragma unroll
    for (int ni = 0; ni < 2; ++ni)
      invf[ni] = exp2f((float)(wn * 32 + ni * 16 + l15) * -LOG2_10000_DIV64);
#pragma unroll
    for (int mi = 0; mi < 4; ++mi)
#pragma unroll
      for (int r = 0; r < 4; ++r) {
        const int s = (m0 + wm * 64 + mi * 16 + quad * 4 + r) & 511;
        const size_t rb = (size_t)s * HD_;
#pragma unroll
        for (int ni = 0; ni < 2; ++ni) {
          const int d = wn * 32 + ni * 16 + l15;  // 0..63
          float sn, cs;
          __sincosf((float)s * invf[ni], &sn, &cs);
          const float x1 = acc[mi][ni][r], x2 = acc[mi][ni + 2][r];
          ob[rb + d] = (f16)(x1 * cs - x2 * sn);
          ob[rb + d + 64] = (f16)(x2 * cs + x1 * sn);
        }
      }
  }
}

// ---------------- flash attention ----------------
// 512 thr = 8 waves; wave owns 16 q-rows. Q/K/V tiles XOR-swizzled in LDS
// (256B rows, chunk c at slot c^(r&15)) -> <=2-way bank aliasing (free).
__global__ __launch_bounds__(512) void attn_kernel(const f16* __restrict__ q,
                                                   const f16* __restrict__ k,
                                                   const f16* __restrict__ vt,
                                                   f16* __restrict__ out) {
  __shared__ __align__(16) f16 Qs[128 * 128];
  __shared__ __align__(16) f16 Ks[128 * 128];
  __shared__ __align__(16) f16 Vs[128 * 128];   // [d][key]
  __shared__ __align__(16) f16 Ps[8][16 * 136];

  const int qt = blockIdx.x, h = blockIdx.y, b = blockIdx.z;
  const int kvh = h >> 2;
  const int tid = threadIdx.x;
  const int wave = tid >> 6, lane = tid & 63;
  const int quad = lane >> 4, l15 = lane & 15;
  const int sm0 = wave * 16;

  const f16* qbase = q + (((size_t)b * NH_ + h) * S_ + qt * 128) * HD_;
  const f16* kbase = k + ((size_t)b * NKV_ + kvh) * S_ * HD_;
  const f16* vbase = vt + ((size_t)b * NKV_ + kvh) * HD_ * S_;

  // stage Q tile, swizzled: LDS chunk L holds global chunk (r, (L&15)^(r&15))
#pragma unroll
  for (int i = 0; i < 4; ++i) {
    const int L = wave * 256 + i * 64 + lane;
    const int r = L >> 4;
    const int c = (L & 15) ^ (r & 15);
    async16(qbase + (size_t)r * HD_ + c * 8, (const char*)Qs + (size_t)(wave * 256 + i * 64) * 16);
  }

  f32x4 O[8] = {};
  float mrun[4], lrun[4];
#pragma unroll
  for (int r = 0; r < 4; ++r) { mrun[r] = -3.0e38f; lrun[r] = 0.f; }

  for (int j = 0; j < 4; ++j) {
    if (j) __syncthreads();  // waves done reading previous K/V tiles
#pragma unroll
    for (int i = 0; i < 4; ++i) {
      const int L = wave * 256 + i * 64 + lane;
      const int r = L >> 4;
      const int c = (L & 15) ^ (r & 15);
      async16(kbase + (size_t)(j * 128 + r) * HD_ + c * 8,
              (const char*)Ks + (size_t)(wave * 256 + i * 64) * 16);
      async16(vbase + (size_t)r * S_ + j * 128 + c * 8,
              (const char*)Vs + (size_t)(wave * 256 + i * 64) * 16);
    }
    __syncthreads();  // drains vmcnt -> tiles visible

    // S = Q @ K^T (16 q-rows per wave x 128 keys)
    f32x4 Sc[8] = {};
#pragma unroll
    for (int ks = 0; ks < 4; ++ks) {
      f16x8 aq, bk[8];
      aq = *reinterpret_cast<const f16x8*>(Qs + ((sm0 + l15) * 16 + (((ks * 4 + quad) ^ l15))) * 8);
#pragma unroll
      for (int ni = 0; ni < 8; ++ni)
        bk[ni] = *reinterpret_cast<const f16x8*>(Ks + ((ni * 16 + l15) * 16 + ((ks * 4 + quad) ^ l15)) * 8);
#pragma unroll
      for (int ni = 0; ni < 8; ++ni)
        Sc[ni] = __builtin_amdgcn_mfma_f32_16x16x32_f16(aq, bk[ni], Sc[ni], 0, 0, 0);
    }

    // online softmax (C-layout: row=quad*4+r, col=ni*16+l15)
#pragma unroll
    for (int r = 0; r < 4; ++r) {
      float mx = -3.0e38f;
#pragma unroll
      for (int ni = 0; ni < 8; ++ni) mx = fmaxf(mx, Sc[ni][r]);
      mx *= ATT_SCALE;
#pragma unroll
      for (int off = 1; off < 16; off <<= 1) mx = fmaxf(mx, __shfl_xor(mx, off));
      const float mnew = fmaxf(mrun[r], mx);
      const float alpha = __expf(mrun[r] - mnew);
      float rs = 0.f;
#pragma unroll
      for (int ni = 0; ni < 8; ++ni) {
        const float pv = __expf(Sc[ni][r] * ATT_SCALE - mnew);
        Sc[ni][r] = pv;
        rs += pv;
      }
#pragma unroll
      for (int off = 1; off < 16; off <<= 1) rs += __shfl_xor(rs, off);
      lrun[r] = lrun[r] * alpha + rs;
      mrun[r] = mnew;
#pragma unroll
      for (int ni = 0; ni < 8; ++ni) O[ni][r] *= alpha;
#pragma unroll
      for (int ni = 0; ni < 8; ++ni)
        Ps[wave][(quad * 4 + r) * 136 + ni * 16 + l15] = (f16)Sc[ni][r];
    }

    // O += P @ V (per-wave P, no barrier needed; Vs rows are d, k-dim = key)
#pragma unroll
    for (int ks = 0; ks < 4; ++ks) {
      f16x8 ap, bv[8];
      ap = *reinterpret_cast<const f16x8*>(&Ps[wave][l15 * 136 + ks * 32 + quad * 8]);
#pragma unroll
      for (int ni = 0; ni < 8; ++ni)
        bv[ni] = *reinterpret_cast<const f16x8*>(Vs + ((ni * 16 + l15) * 16 + ((ks * 4 + quad) ^ l15)) * 8);
#pragma unroll
      for (int ni = 0; ni < 8; ++ni)
        O[ni] = __builtin_amdgcn_mfma_f32_16x16x32_f16(ap, bv[ni], O[ni], 0, 0, 0);
    }
  }

  // epilogue: normalize, write attn[b, s, h*128 + d]
#pragma unroll
  for (int r = 0; r < 4; ++r) {
    const float inv = 1.f / lrun[r];
    const int srow = qt * 128 + sm0 + quad * 4 + r;
#pragma unroll
    for (int ni = 0; ni < 8; ++ni)
      out[((size_t)b * S_ + srow) * H_ + h * HD_ + ni * 16 + l15] = (f16)(O[ni][r] * inv);
  }
}

// ---------------- GEMM2: out = attn @ Wo^T (fp32 out) ----------------
__global__ __launch_bounds__(256, 5) void gemm_out(const f16* __restrict__ A,
                                                   const f16* __restrict__ W,
                                                   float* __restrict__ out) {
  __shared__ __align__(16) f16 As[128 * 32];
  __shared__ __align__(16) f16 Bs[128 * 32];
  const int K = 2048;
  const int m0 = blockIdx.x * 128;
  const int n0 = blockIdx.y * 128;
  const int tid = threadIdx.x;
  const int wave = tid >> 6, lane = tid & 63;
  const int quad = lane >> 4, l15 = lane & 15;
  const int wm = wave >> 1, wn = wave & 1;
  const int G0 = wave * 128 + lane;
  const int r0 = G0 >> 2, c0g = swz(r0, G0 & 3);
  const int r1 = (G0 + 64) >> 2, c1g = swz(r1, (G0 + 64) & 3);

  f32x4 acc[4][4] = {};

  for (int k0 = 0; k0 < K; k0 += 32) {
    async16(A + (size_t)(m0 + r0) * K + k0 + c0g * 8, (const char*)As + (size_t)G0 * 16);
    async16(A + (size_t)(m0 + r1) * K + k0 + c1g * 8, (const char*)As + (size_t)(G0 + 64) * 16);
    async16(W + (size_t)(n0 + r0) * K + k0 + c0g * 8, (const char*)Bs + (size_t)G0 * 16);
    async16(W + (size_t)(n0 + r1) * K + k0 + c1g * 8, (const char*)Bs + (size_t)(G0 + 64) * 16);
    __syncthreads();
    f16x8 b[4];
#pragma unroll
    for (int ni = 0; ni < 4; ++ni) {
      const int col = wn * 64 + ni * 16 + l15;
      b[ni] = *reinterpret_cast<const f16x8*>(Bs + col * 32 + swz(col, quad) * 8);
    }
#pragma unroll
    for (int mi = 0; mi < 4; ++mi) {
      const int row = wm * 64 + mi * 16 + l15;
      const f16x8 a = *reinterpret_cast<const f16x8*>(As + row * 32 + swz(row, quad) * 8);
#pragma unroll
      for (int ni = 0; ni < 4; ++ni)
        acc[mi][ni] = __builtin_amdgcn_mfma_f32_16x16x32_f16(a, b[ni], acc[mi][ni], 0, 0, 0);
    }
    __syncthreads();
  }

#pragma unroll
  for (int mi = 0; mi < 4; ++mi) {
#pragma unroll
    for (int ni = 0; ni < 4; ++ni) {
      const int ncol = n0 + wn * 64 + ni * 16 + l15;
#pragma unroll
      for (int r = 0; r < 4; ++r) {
        const int mrow = m0 + wm * 64 + mi * 16 + quad * 4 + r;
        out[(size_t)mrow * 2048 + ncol] = acc[mi][ni][r];
      }
    }
  }
}

extern "C" void kernel_launch(void* const* d_in, const int* in_sizes, int n_in,
                              void* d_out, int out_size, void* d_ws, size_t ws_size,
                              hipStream_t stream) {
  const float* x = (const float*)d_in[0];
  const float* Wq = (const float*)d_in[1];
  const float* Wk = (const float*)d_in[2];
  const float* Wv = (const float*)d_in[3];
  const float* Wo = (const float*)d_in[4];
  float* out = (float*)d_out;
  char* ws = (char*)d_ws;

  f16* x_h  = (f16*)(ws + 0);
  f16* w_h  = (f16*)(ws + 33554432);
  f16* wo_h = (f16*)(ws + 46137344);
  f16* qb   = (f16*)(ws + 54525952);
  f16* kb   = (f16*)(ws + 88080384);
  f16* vtb  = (f16*)(ws + 96468992);
  f16* attn = (f16*)(ws + 104857600);  // needs ws_size >= 138412032

  cast_all<<<26624, 256, 0, stream>>>(x, Wq, Wk, Wv, Wo, x_h, w_h, wo_h);
  gemm_qkv<<<dim3(64, 24), 256, 0, stream>>>(x_h, w_h, qb, kb, vtb);
  attn_kernel<<<dim3(4, 16, 16), 512, 0, stream>>>(qb, kb, vtb, attn);
  gemm_out<<<dim3(64, 16), 256, 0, stream>>>(attn, wo_h, out);
}

// Round 5
// 455.091 us; speedup vs baseline: 1.9947x; 1.9947x over previous
//
#include <hip/hip_runtime.h>
#include <stdint.h>

// Problem: B=16, S=512, H=2048, NH=16, NKV=4, HD=128
// out = Wo-proj( softmax(rope(q) @ rope(k)^T * hd^-.5) @ v )  with GQA rep=4
//
// ws layout (f16 intermediates):
//   x_h   [8192,2048]        @ 0
//   w_h   [3072,2048]        @ 33554432  (Wq 0..2047, Wk 2048..2559, Wv 2560..3071)
//   wo_h  [2048,2048]        @ 46137344
//   q     [16,16,512,128]    @ 54525952   (RoPE fused in gemm_qkv epilogue)
//   k     [16,4,512,128]     @ 88080384   (RoPE fused)
//   vt    [16,4,128,512]     @ 96468992   (V transposed)
//   attn  [8192,2048]        @ 104857600
//
// R3 lesson: occupancy > bank conflicts; CSV VGPR_Count EXCLUDES the 64 AGPR
//   accumulators (R2 "76" = 140 unified).
// R4 lesson: NEVER put min-waves __launch_bounds__ on an MFMA kernel with a
//   big acc tile — (256,5) spilled acc to scratch (WRITE 49KB->1.28GB, 554us).
// R5: R2's proven 2x8 gemm_qkv + swizzle ONLY (single-variable); plain bounds.

typedef _Float16 f16;
typedef _Float16 f16x4 __attribute__((ext_vector_type(4)));
typedef _Float16 f16x8 __attribute__((ext_vector_type(8)));
typedef float f32x4 __attribute__((ext_vector_type(4)));

#define B_   16
#define S_   512
#define H_   2048
#define NH_  16
#define NKV_ 4
#define HD_  128
#define ATT_SCALE 0.08838834764831843f
#define LOG2_10000_DIV64 0.20762050593045952f

#define AS1 __attribute__((address_space(1)))
#define AS3 __attribute__((address_space(3)))

// async global->LDS, 16B/lane. LDS dest must be wave-uniform; HW adds lane*16.
__device__ __forceinline__ void async16(const void* g, const void* l) {
  __builtin_amdgcn_global_load_lds((const AS1 unsigned int*)(uintptr_t)g,
                                   (AS3 unsigned int*)(uintptr_t)l, 16, 0, 0);
}

// ---------------- fused fp32 -> f16 cast for all 5 inputs ----------------
__global__ __launch_bounds__(256) void cast_all(const float* __restrict__ x,
                                                const float* __restrict__ wq,
                                                const float* __restrict__ wk,
                                                const float* __restrict__ wv,
                                                const float* __restrict__ wo,
                                                f16* __restrict__ x_h,
                                                f16* __restrict__ w_h,
                                                f16* __restrict__ wo_h) {
  const int i = blockIdx.x * 256 + threadIdx.x;
  const float4* src;
  f16x4* dst;
  if (i < 4194304) {                 // x: 8192*2048
    src = (const float4*)x + i;            dst = (f16x4*)x_h + i;
  } else if (i < 5242880) {          // Wq: 2048*2048
    int j = i - 4194304;
    src = (const float4*)wq + j;           dst = (f16x4*)w_h + j;
  } else if (i < 5505024) {          // Wk: 512*2048
    int j = i - 5242880;
    src = (const float4*)wk + j;           dst = (f16x4*)w_h + 1048576 + j;
  } else if (i < 5767168) {          // Wv: 512*2048
    int j = i - 5505024;
    src = (const float4*)wv + j;           dst = (f16x4*)w_h + 1310720 + j;
  } else {                           // Wo: 2048*2048
    int j = i - 5767168;
    src = (const float4*)wo + j;           dst = (f16x4*)wo_h + j;
  }
  float4 v = *src;
  f16x4 o = {(f16)v.x, (f16)v.y, (f16)v.z, (f16)v.w};
  *dst = o;
}

// LDS chunk swizzle for 64B-row tiles: chunk (r,c) at slot c ^ ((r>>1)&3).
// Involutive; staging stays lds-linear (swizzle folded into global address).
__device__ __forceinline__ int swz(int r, int c) { return c ^ ((r >> 1) & 3); }

// ---------------- GEMM1: qkv = x @ Wqkv^T, fused RoPE + scatter epilogue ----
// R2's 2x8 wave tiling (wave = 32 rows x 128 cols -> block col range = one
// head, RoPE pair (d,d+64) = acc[mi][ni]/acc[mi][ni+4] same lane) + swizzle.
__global__ __launch_bounds__(256) void gemm_qkv(const f16* __restrict__ A,
                                                const f16* __restrict__ W,
                                                f16* __restrict__ qo,
                                                f16* __restrict__ ko,
                                                f16* __restrict__ vto) {
  __shared__ __align__(16) f16 As[128 * 32];
  __shared__ __align__(16) f16 Bs[128 * 32];
  const int K = 2048;
  const int m0 = blockIdx.x * 128;
  const int n0 = blockIdx.y * 128;
  const int tid = threadIdx.x;
  const int wave = tid >> 6, lane = tid & 63;
  const int quad = lane >> 4, l15 = lane & 15;
  const int G0 = wave * 128 + lane;
  const int r0 = G0 >> 2, c0g = swz(r0, G0 & 3);
  const int r1 = (G0 + 64) >> 2, c1g = swz(r1, (G0 + 64) & 3);

  f32x4 acc[2][8] = {};

  for (int k0 = 0; k0 < K; k0 += 32) {
    async16(A + (size_t)(m0 + r0) * K + k0 + c0g * 8, (const char*)As + (size_t)G0 * 16);
    async16(A + (size_t)(m0 + r1) * K + k0 + c1g * 8, (const char*)As + (size_t)(G0 + 64) * 16);
    async16(W + (size_t)(n0 + r0) * K + k0 + c0g * 8, (const char*)Bs + (size_t)G0 * 16);
    async16(W + (size_t)(n0 + r1) * K + k0 + c1g * 8, (const char*)Bs + (size_t)(G0 + 64) * 16);
    __syncthreads();  // drains vmcnt -> staging visible
    f16x8 a[2], b[8];
#pragma unroll
    for (int mi = 0; mi < 2; ++mi) {
      const int row = wave * 32 + mi * 16 + l15;
      a[mi] = *reinterpret_cast<const f16x8*>(As + row * 32 + swz(row, quad) * 8);
    }
#pragma unroll
    for (int ni = 0; ni < 8; ++ni) {
      const int col = ni * 16 + l15;
      b[ni] = *reinterpret_cast<const f16x8*>(Bs + col * 32 + swz(col, quad) * 8);
    }
#pragma unroll
    for (int mi = 0; mi < 2; ++mi)
#pragma unroll
      for (int ni = 0; ni < 8; ++ni)
        acc[mi][ni] = __builtin_amdgcn_mfma_f32_16x16x32_f16(a[mi], b[ni], acc[mi][ni], 0, 0, 0);
    __syncthreads();  // before next-tile overwrite
  }

  const int b_ = m0 >> 9;  // batch (uniform per block)
  if (n0 >= 2560) {
    // ---- V: no rope, store transposed [b, kh, d, s] ----
    const int h = (n0 - 2560) >> 7;
    f16* vb = vto + ((size_t)b_ * NKV_ + h) * HD_ * S_;
#pragma unroll
    for (int mi = 0; mi < 2; ++mi)
#pragma unroll
      for (int r = 0; r < 4; ++r) {
        const int s = (m0 + wave * 32 + mi * 16 + quad * 4 + r) & 511;
#pragma unroll
        for (int ni = 0; ni < 8; ++ni) {
          const int d = ni * 16 + l15;
          vb[(size_t)d * S_ + s] = (f16)acc[mi][ni][r];
        }
      }
  } else {
    // ---- Q or K: fused RoPE, store [b, h, s, d] ----
    f16* ob = (n0 < 2048) ? (qo + ((size_t)b_ * NH_ + (n0 >> 7)) * S_ * HD_)
                          : (ko + ((size_t)b_ * NKV_ + ((n0 - 2048) >> 7)) * S_ * HD_);
    float invf[4];
#pragma unroll
    for (int ni = 0; ni < 4; ++ni)
      invf[ni] = exp2f((float)(ni * 16 + l15) * -LOG2_10000_DIV64);
#pragma unroll
    for (int mi = 0; mi < 2; ++mi)
#pragma unroll
      for (int r = 0; r < 4; ++r) {
        const int s = (m0 + wave * 32 + mi * 16 + quad * 4 + r) & 511;
        const size_t rb = (size_t)s * HD_;
#pragma unroll
        for (int ni = 0; ni < 4; ++ni) {
          const int d = ni * 16 + l15;  // 0..63
          float sn, cs;
          __sincosf((float)s * invf[ni], &sn, &cs);
          const float x1 = acc[mi][ni][r], x2 = acc[mi][ni + 4][r];
          ob[rb + d] = (f16)(x1 * cs - x2 * sn);
          ob[rb + d + 64] = (f16)(x2 * cs + x1 * sn);
        }
      }
  }
}

// ---------------- flash attention ----------------
// 512 thr = 8 waves; wave owns 16 q-rows. Q/K/V tiles XOR-swizzled in LDS
// (256B rows, chunk c at slot c^(r&15)) -> <=2-way bank aliasing (free).
__global__ __launch_bounds__(512) void attn_kernel(const f16* __restrict__ q,
                                                   const f16* __restrict__ k,
                                                   const f16* __restrict__ vt,
                                                   f16* __restrict__ out) {
  __shared__ __align__(16) f16 Qs[128 * 128];
  __shared__ __align__(16) f16 Ks[128 * 128];
  __shared__ __align__(16) f16 Vs[128 * 128];   // [d][key]
  __shared__ __align__(16) f16 Ps[8][16 * 136];

  const int qt = blockIdx.x, h = blockIdx.y, b = blockIdx.z;
  const int kvh = h >> 2;
  const int tid = threadIdx.x;
  const int wave = tid >> 6, lane = tid & 63;
  const int quad = lane >> 4, l15 = lane & 15;
  const int sm0 = wave * 16;

  const f16* qbase = q + (((size_t)b * NH_ + h) * S_ + qt * 128) * HD_;
  const f16* kbase = k + ((size_t)b * NKV_ + kvh) * S_ * HD_;
  const f16* vbase = vt + ((size_t)b * NKV_ + kvh) * HD_ * S_;

  // stage Q tile, swizzled: LDS chunk L holds global chunk (r, (L&15)^(r&15))
#pragma unroll
  for (int i = 0; i < 4; ++i) {
    const int L = wave * 256 + i * 64 + lane;
    const int r = L >> 4;
    const int c = (L & 15) ^ (r & 15);
    async16(qbase + (size_t)r * HD_ + c * 8, (const char*)Qs + (size_t)(wave * 256 + i * 64) * 16);
  }

  f32x4 O[8] = {};
  float mrun[4], lrun[4];
#pragma unroll
  for (int r = 0; r < 4; ++r) { mrun[r] = -3.0e38f; lrun[r] = 0.f; }

  for (int j = 0; j < 4; ++j) {
    if (j) __syncthreads();  // waves done reading previous K/V tiles
#pragma unroll
    for (int i = 0; i < 4; ++i) {
      const int L = wave * 256 + i * 64 + lane;
      const int r = L >> 4;
      const int c = (L & 15) ^ (r & 15);
      async16(kbase + (size_t)(j * 128 + r) * HD_ + c * 8,
              (const char*)Ks + (size_t)(wave * 256 + i * 64) * 16);
      async16(vbase + (size_t)r * S_ + j * 128 + c * 8,
              (const char*)Vs + (size_t)(wave * 256 + i * 64) * 16);
    }
    __syncthreads();  // drains vmcnt -> tiles visible

    // S = Q @ K^T (16 q-rows per wave x 128 keys)
    f32x4 Sc[8] = {};
#pragma unroll
    for (int ks = 0; ks < 4; ++ks) {
      f16x8 aq, bk[8];
      aq = *reinterpret_cast<const f16x8*>(Qs + ((sm0 + l15) * 16 + (((ks * 4 + quad) ^ l15))) * 8);
#pragma unroll
      for (int ni = 0; ni < 8; ++ni)
        bk[ni] = *reinterpret_cast<const f16x8*>(Ks + ((ni * 16 + l15) * 16 + ((ks * 4 + quad) ^ l15)) * 8);
#pragma unroll
      for (int ni = 0; ni < 8; ++ni)
        Sc[ni] = __builtin_amdgcn_mfma_f32_16x16x32_f16(aq, bk[ni], Sc[ni], 0, 0, 0);
    }

    // online softmax (C-layout: row=quad*4+r, col=ni*16+l15)
#pragma unroll
    for (int r = 0; r < 4; ++r) {
      float mx = -3.0e38f;
#pragma unroll
      for (int ni = 0; ni < 8; ++ni) mx = fmaxf(mx, Sc[ni][r]);
      mx *= ATT_SCALE;
#pragma unroll
      for (int off = 1; off < 16; off <<= 1) mx = fmaxf(mx, __shfl_xor(mx, off));
      const float mnew = fmaxf(mrun[r], mx);
      const float alpha = __expf(mrun[r] - mnew);
      float rs = 0.f;
#pragma unroll
      for (int ni = 0; ni < 8; ++ni) {
        const float pv = __expf(Sc[ni][r] * ATT_SCALE - mnew);
        Sc[ni][r] = pv;
        rs += pv;
      }
#pragma unroll
      for (int off = 1; off < 16; off <<= 1) rs += __shfl_xor(rs, off);
      lrun[r] = lrun[r] * alpha + rs;
      mrun[r] = mnew;
#pragma unroll
      for (int ni = 0; ni < 8; ++ni) O[ni][r] *= alpha;
#pragma unroll
      for (int ni = 0; ni < 8; ++ni)
        Ps[wave][(quad * 4 + r) * 136 + ni * 16 + l15] = (f16)Sc[ni][r];
    }

    // O += P @ V (per-wave P, no barrier needed; Vs rows are d, k-dim = key)
#pragma unroll
    for (int ks = 0; ks < 4; ++ks) {
      f16x8 ap, bv[8];
      ap = *reinterpret_cast<const f16x8*>(&Ps[wave][l15 * 136 + ks * 32 + quad * 8]);
#pragma unroll
      for (int ni = 0; ni < 8; ++ni)
        bv[ni] = *reinterpret_cast<const f16x8*>(Vs + ((ni * 16 + l15) * 16 + ((ks * 4 + quad) ^ l15)) * 8);
#pragma unroll
      for (int ni = 0; ni < 8; ++ni)
        O[ni] = __builtin_amdgcn_mfma_f32_16x16x32_f16(ap, bv[ni], O[ni], 0, 0, 0);
    }
  }

  // epilogue: normalize, write attn[b, s, h*128 + d]
#pragma unroll
  for (int r = 0; r < 4; ++r) {
    const float inv = 1.f / lrun[r];
    const int srow = qt * 128 + sm0 + quad * 4 + r;
#pragma unroll
    for (int ni = 0; ni < 8; ++ni)
      out[((size_t)b * S_ + srow) * H_ + h * HD_ + ni * 16 + l15] = (f16)(O[ni][r] * inv);
  }
}

// ---------------- GEMM2: out = attn @ Wo^T (fp32 out) ----------------
__global__ __launch_bounds__(256) void gemm_out(const f16* __restrict__ A,
                                                const f16* __restrict__ W,
                                                float* __restrict__ out) {
  __shared__ __align__(16) f16 As[128 * 32];
  __shared__ __align__(16) f16 Bs[128 * 32];
  const int K = 2048;
  const int m0 = blockIdx.x * 128;
  const int n0 = blockIdx.y * 128;
  const int tid = threadIdx.x;
  const int wave = tid >> 6, lane = tid & 63;
  const int quad = lane >> 4, l15 = lane & 15;
  const int wm = wave >> 1, wn = wave & 1;
  const int G0 = wave * 128 + lane;
  const int r0 = G0 >> 2, c0g = swz(r0, G0 & 3);
  const int r1 = (G0 + 64) >> 2, c1g = swz(r1, (G0 + 64) & 3);

  f32x4 acc[4][4] = {};

  for (int k0 = 0; k0 < K; k0 += 32) {
    async16(A + (size_t)(m0 + r0) * K + k0 + c0g * 8, (const char*)As + (size_t)G0 * 16);
    async16(A + (size_t)(m0 + r1) * K + k0 + c1g * 8, (const char*)As + (size_t)(G0 + 64) * 16);
    async16(W + (size_t)(n0 + r0) * K + k0 + c0g * 8, (const char*)Bs + (size_t)G0 * 16);
    async16(W + (size_t)(n0 + r1) * K + k0 + c1g * 8, (const char*)Bs + (size_t)(G0 + 64) * 16);
    __syncthreads();
    f16x8 a[4], b[4];
#pragma unroll
    for (int mi = 0; mi < 4; ++mi) {
      const int row = wm * 64 + mi * 16 + l15;
      a[mi] = *reinterpret_cast<const f16x8*>(As + row * 32 + swz(row, quad) * 8);
    }
#pragma unroll
    for (int ni = 0; ni < 4; ++ni) {
      const int col = wn * 64 + ni * 16 + l15;
      b[ni] = *reinterpret_cast<const f16x8*>(Bs + col * 32 + swz(col, quad) * 8);
    }
#pragma unroll
    for (int mi = 0; mi < 4; ++mi)
#pragma unroll
      for (int ni = 0; ni < 4; ++ni)
        acc[mi][ni] = __builtin_amdgcn_mfma_f32_16x16x32_f16(a[mi], b[ni], acc[mi][ni], 0, 0, 0);
    __syncthreads();
  }

#pragma unroll
  for (int mi = 0; mi < 4; ++mi) {
#pragma unroll
    for (int ni = 0; ni < 4; ++ni) {
      const int ncol = n0 + wn * 64 + ni * 16 + l15;
#pragma unroll
      for (int r = 0; r < 4; ++r) {
        const int mrow = m0 + wm * 64 + mi * 16 + quad * 4 + r;
        out[(size_t)mrow * 2048 + ncol] = acc[mi][ni][r];
      }
    }
  }
}

extern "C" void kernel_launch(void* const* d_in, const int* in_sizes, int n_in,
                              void* d_out, int out_size, void* d_ws, size_t ws_size,
                              hipStream_t stream) {
  const float* x = (const float*)d_in[0];
  const float* Wq = (const float*)d_in[1];
  const float* Wk = (const float*)d_in[2];
  const float* Wv = (const float*)d_in[3];
  const float* Wo = (const float*)d_in[4];
  float* out = (float*)d_out;
  char* ws = (char*)d_ws;

  f16* x_h  = (f16*)(ws + 0);
  f16* w_h  = (f16*)(ws + 33554432);
  f16* wo_h = (f16*)(ws + 46137344);
  f16* qb   = (f16*)(ws + 54525952);
  f16* kb   = (f16*)(ws + 88080384);
  f16* vtb  = (f16*)(ws + 96468992);
  f16* attn = (f16*)(ws + 104857600);  // needs ws_size >= 138412032

  cast_all<<<26624, 256, 0, stream>>>(x, Wq, Wk, Wv, Wo, x_h, w_h, wo_h);
  gemm_qkv<<<dim3(64, 24), 256, 0, stream>>>(x_h, w_h, qb, kb, vtb);
  attn_kernel<<<dim3(4, 16, 16), 512, 0, stream>>>(qb, kb, vtb, attn);
  gemm_out<<<dim3(64, 16), 256, 0, stream>>>(attn, wo_h, out);
}